// Round 21
// baseline (303.436 us; speedup 1.0000x reference)
//
#include <hip/hip_runtime.h>
#include <hip/hip_bf16.h>

#define PP 4096          // H*W
#define HH 64
#define WW 64

typedef __attribute__((ext_vector_type(8))) short short8b;   // 8 bf16
typedef __attribute__((ext_vector_type(4))) float f32x4;

static __device__ __forceinline__ float bf2f(short s) {
    union { unsigned int u; float f; } cv; cv.u = ((unsigned int)(unsigned short)s) << 16; return cv.f;
}
static __device__ __forceinline__ short f2bf(float f) {
    __hip_bfloat16 h = __float2bfloat16(f);
    return *reinterpret_cast<short*>(&h);
}

// ---------------------------------------------------------------------------
// Merged weight-prep (R15-validated): 5 1x1 packs + conv3 A-frag pack.
// ---------------------------------------------------------------------------
static __device__ __forceinline__ void pack16(const float* __restrict__ W,
                                              short* __restrict__ dst,
                                              int MT, int K, int s) {
    int total = MT * 2 * (K / 64) * 64;
    if (s >= total) return;
    int lane = s & 63;
    int rest = s >> 6;
    int ks = rest & 1; rest >>= 1;
    int mt = rest % MT;
    int cc = rest / MT;
    int o   = mt * 16 + (lane & 15);
    int ch0 = cc * 64 + ks * 32 + (lane >> 4) * 8;
    short8b v;
    #pragma unroll
    for (int j = 0; j < 8; ++j) v[j] = f2bf(W[(size_t)o * K + ch0 + j]);
    ((short8b*)dst)[s] = v;
}

__global__ void k_packall(const float* __restrict__ Wt1, const float* __restrict__ WU,
                          const float* __restrict__ WV, const float* __restrict__ Wa1,
                          const float* __restrict__ Wa2, const float* __restrict__ Wot,
                          short* __restrict__ Wt1p, short* __restrict__ WUp,
                          short* __restrict__ WVp, short* __restrict__ Wa1p,
                          short* __restrict__ Wa2p, short* __restrict__ Wotp) {
    int b = blockIdx.x, tid = threadIdx.x;
    if (b < 96)       { pack16(Wt1, Wt1p, 16, 768, (b)       * 256 + tid); }
    else if (b < 128) { pack16(WU,  WUp,  16, 256, (b - 96)  * 256 + tid); }
    else if (b < 144) { pack16(WV,  WVp,   8, 256, (b - 128) * 256 + tid); }
    else if (b < 184) { pack16(Wa1, Wa1p,  8, 640, (b - 144) * 256 + tid); }
    else if (b < 224) { pack16(Wa2, Wa2p, 40, 128, (b - 184) * 256 + tid); }
    else {
        int s = (b - 224) * 256 + tid;
        int lane = s & 63;
        int rest = s >> 6;
        int ks = rest & 1;  rest >>= 1;
        int mt = rest & 15; rest >>= 4;
        int cc = rest % 10;
        int k9 = rest / 10;
        int o   = mt * 16 + (lane & 15);
        int ch0 = cc * 64 + ks * 32 + (lane >> 4) * 8;
        short8b v{};
        #pragma unroll
        for (int j = 0; j < 8; ++j)
            v[j] = f2bf(Wot[((size_t)o * 640 + ch0 + j) * 9 + k9]);
        ((short8b*)Wotp)[s] = v;
    }
}

// ---------------------------------------------------------------------------
// Merged f32 NCHW -> bf16 NHWC transposes (t_hx, tx). Grid (64, 8, 8) x 256.
// ---------------------------------------------------------------------------
__global__ void k_t2h_all(const float* __restrict__ t_hx, const float* __restrict__ tx,
                          short* __restrict__ txc, short* __restrict__ txh) {
    __shared__ short T[64 * 65];
    int tid = threadIdx.x;
    int by = blockIdx.y;
    const float* src; short* dst; int P, pitch, yb;
    if (by < 4)  { src = t_hx; dst = txc; P = 4096; pitch = 512; yb = by; }
    else { if (blockIdx.x >= 16) return;
           src = tx;   dst = txh; P = 1024; pitch = 256; yb = by - 4; }
    int p0 = blockIdx.x * 64, c0 = yb * 64, n = blockIdx.z;
    #pragma unroll
    for (int it = 0; it < 16; ++it) {
        int slot = it * 256 + tid;
        int ch = slot >> 6, px = slot & 63;
        T[ch * 65 + px] = f2bf(src[((size_t)(n * 256 + c0 + ch)) * P + p0 + px]);
    }
    __syncthreads();
    #pragma unroll
    for (int it = 0; it < 16; ++it) {
        int slot = it * 256 + tid;
        int px = slot >> 6, ch = slot & 63;
        dst[((size_t)n * P + p0 + px) * pitch + c0 + ch] = T[ch * 65 + px];
    }
}

// ---------------------------------------------------------------------------
// Bilinear 2x upsample (align_corners) txh NHWC [n][1024][256] -> txc cols 256..511.
// ---------------------------------------------------------------------------
__global__ void k_up(const short* __restrict__ txh, short* __restrict__ txc) {
    int tid = threadIdx.x;
    int cg = tid & 31, pxl = tid >> 5;
    int px = blockIdx.x * 8 + pxl;
    int n  = blockIdx.z;
    int y = px >> 6, x = px & 63;
    const float s = 31.0f / 63.0f;
    float fy = y * s, fx = x * s;
    int y0 = (int)fy, x0 = (int)fx;
    int y1 = min(y0 + 1, 31), x1 = min(x0 + 1, 31);
    float wy = fy - (float)y0, wx = fx - (float)x0;
    const short8b* base = (const short8b*)(txh + ((size_t)n * 1024) * 256);
    short8b a = base[((size_t)(y0 * 32 + x0) * 256 + cg * 8) >> 3];
    short8b b = base[((size_t)(y0 * 32 + x1) * 256 + cg * 8) >> 3];
    short8b c = base[((size_t)(y1 * 32 + x0) * 256 + cg * 8) >> 3];
    short8b d = base[((size_t)(y1 * 32 + x1) * 256 + cg * 8) >> 3];
    short8b r;
    #pragma unroll
    for (int j = 0; j < 8; ++j) {
        float v = (bf2f(a[j]) * (1.f - wy) + bf2f(c[j]) * wy) * (1.f - wx)
                + (bf2f(b[j]) * (1.f - wy) + bf2f(d[j]) * wy) * wx;
        r[j] = f2bf(v);
    }
    *(short8b*)(txc + ((size_t)n * PP + px) * 512 + 256 + cg * 8) = r;
}

// ---------------------------------------------------------------------------
// GEMM LDS staging helpers (R15/R16-validated).
// ---------------------------------------------------------------------------
static __device__ __forceinline__ void stage64(const short* __restrict__ src, int pitch,
                                               int c0, size_t rowbase, short* lds, int tid) {
    #pragma unroll
    for (int it = 0; it < 4; ++it) {
        int idx = it * 256 + tid;
        int px = idx >> 3, cg = idx & 7;
        short8b v = *(const short8b*)(src + (rowbase + px) * (size_t)pitch + c0 + cg * 8);
        int elem = (px * 64 + cg * 8) ^ ((px & 7) << 3);
        *(short8b*)&lds[elem] = v;
    }
}
static __device__ __forceinline__ void stage64f(const float* __restrict__ ten, int C,
                                                int c0, int n, int pxbase,
                                                short* lds, int tid) {
    int chp = tid & 31;
    int pxg = tid >> 5;
    const float* p0 = ten + ((size_t)(n * C + c0 + chp * 2)) * PP + pxbase + pxg * 16;
    const float* p1 = p0 + PP;
    #pragma unroll
    for (int kq = 0; kq < 4; ++kq) {
        f32x4 a = *(const f32x4*)(p0 + kq * 4);
        f32x4 b = *(const f32x4*)(p1 + kq * 4);
        #pragma unroll
        for (int j = 0; j < 4; ++j) {
            int px = pxg * 16 + kq * 4 + j;
            int idx = px * 64 + ((chp * 2) ^ ((px & 7) << 3));
            unsigned int u = (unsigned int)(unsigned short)f2bf(a[j])
                           | ((unsigned int)(unsigned short)f2bf(b[j]) << 16);
            *(unsigned int*)&lds[idx] = u;
        }
    }
}
static __device__ __forceinline__ short8b afrag(const short* lds, int pw, int mf, int ks, int lane) {
    int px = pw * 64 + mf * 16 + (lane & 15);
    int elem = (px * 64 + ks * 32 + ((lane >> 4) * 8)) ^ ((px & 7) << 3);
    return *(const short8b*)&lds[elem];
}
// XCD co-residency (R20-validated): pt on blockIdx.x, bx on blockIdx.y.
#define GEMM_PROLOG \
    int tid = threadIdx.x, lane = tid & 63, wid = tid >> 6; \
    int pw = wid & 1, ow = wid >> 1; \
    int bx = blockIdx.y, pt = blockIdx.x, n = blockIdx.z; \
    size_t rowbase = (size_t)n * PP + pt * 128; \
    f32x4 acc[4][4] = {}; (void)bx; (void)rowbase;
#define GEMM_STEP(MT) { \
    short8b afr[4][2], bfr[4][2]; \
    _Pragma("unroll") for (int mf = 0; mf < 4; ++mf) \
        _Pragma("unroll") for (int ks = 0; ks < 2; ++ks) afr[mf][ks] = afrag(lds, pw, mf, ks, lane); \
    _Pragma("unroll") for (int nf = 0; nf < 4; ++nf) { \
        int mt_g = bx * 8 + ow * 4 + nf; \
        _Pragma("unroll") for (int ks = 0; ks < 2; ++ks) \
            bfr[nf][ks] = wfv[(((size_t)cc * (MT) + mt_g) * 2 + ks) * 64 + lane]; } \
    _Pragma("unroll") for (int ks = 0; ks < 2; ++ks) \
        _Pragma("unroll") for (int mf = 0; mf < 4; ++mf) \
            _Pragma("unroll") for (int nf = 0; nf < 4; ++nf) \
                acc[mf][nf] = __builtin_amdgcn_mfma_f32_16x16x32_bf16(afr[mf][ks], bfr[nf][ks], acc[mf][nf], 0, 0, 0); }

// ---------------------------------------------------------------------------
// GAP GEMM: K=768 ([sx1 f32-direct; txc]); relu+px-sum -> part.
// ---------------------------------------------------------------------------
__global__ __launch_bounds__(256) void k_gemm_gap(const float* __restrict__ sx1,
        const short* __restrict__ txc, const short* __restrict__ wf,
        const float* __restrict__ bias, float* __restrict__ part) {
    __shared__ short lds[128 * 64];
    __shared__ float red[128 * 2];
    GEMM_PROLOG
    const short8b* wfv = (const short8b*)wf;
    for (int cc = 0; cc < 12; ++cc) {
        __syncthreads();
        if (cc < 4) stage64f(sx1, 256, cc * 64, n, pt * 128, lds, tid);
        else        stage64(txc, 512, (cc - 4) * 64, rowbase, lds, tid);
        __syncthreads();
        GEMM_STEP(16)
    }
    #pragma unroll
    for (int nf = 0; nf < 4; ++nf) {
        int o = bx * 128 + ow * 64 + nf * 16 + (lane & 15);
        float b = bias[o];
        float s = 0.f;
        #pragma unroll
        for (int mf = 0; mf < 4; ++mf)
            #pragma unroll
            for (int r = 0; r < 4; ++r) {
                float v = acc[mf][nf][r] + b;
                s += v > 0.f ? v : 0.f;
            }
        s += __shfl_xor(s, 16);
        s += __shfl_xor(s, 32);
        if (lane < 16) red[(ow * 64 + nf * 16 + lane) * 2 + pw] = s;
    }
    __syncthreads();
    if (tid < 128)
        part[((size_t)n * 256 + bx * 128 + tid) * 32 + pt] = red[tid * 2] + red[tid * 2 + 1];
}

// ---------------------------------------------------------------------------
// bU GEMM: K=256 (sx2 f32-direct); relu(+bias)*wvec -> bUh NHWC.
// ---------------------------------------------------------------------------
__global__ __launch_bounds__(256) void k_gemm_bU(const float* __restrict__ sx2,
        const short* __restrict__ wf, const float* __restrict__ bias,
        const float* __restrict__ wvec, short* __restrict__ bUh) {
    __shared__ short lds[128 * 64];
    GEMM_PROLOG
    const short8b* wfv = (const short8b*)wf;
    for (int cc = 0; cc < 4; ++cc) {
        __syncthreads();
        stage64f(sx2, 256, cc * 64, n, pt * 128, lds, tid);
        __syncthreads();
        GEMM_STEP(16)
    }
    #pragma unroll
    for (int nf = 0; nf < 4; ++nf) {
        int o = bx * 128 + ow * 64 + nf * 16 + (lane & 15);
        float b = bias[o], wv = wvec[n * 256 + o];
        #pragma unroll
        for (int mf = 0; mf < 4; ++mf)
            #pragma unroll
            for (int r = 0; r < 4; ++r) {
                int px = pw * 64 + mf * 16 + (lane >> 4) * 4 + r;
                float v = acc[mf][nf][r] + b;
                v = v > 0.f ? v : 0.f;
                bUh[(rowbase + px) * 256 + o] = f2bf(v * wv);
            }
    }
}

// ---------------------------------------------------------------------------
// bV GEMM: M=128, K=256 (bUh); relu -> bVh [n][px][128].
// ---------------------------------------------------------------------------
__global__ __launch_bounds__(256) void k_gemm_bV(const short* __restrict__ bUh,
        const short* __restrict__ wf, const float* __restrict__ bias,
        short* __restrict__ bVh) {
    __shared__ short lds[128 * 64];
    GEMM_PROLOG
    const short8b* wfv = (const short8b*)wf;
    for (int cc = 0; cc < 4; ++cc) {
        __syncthreads();
        stage64(bUh, 256, cc * 64, rowbase, lds, tid);
        __syncthreads();
        GEMM_STEP(8)
    }
    #pragma unroll
    for (int nf = 0; nf < 4; ++nf) {
        int o = ow * 64 + nf * 16 + (lane & 15);
        float b = bias[o];
        #pragma unroll
        for (int mf = 0; mf < 4; ++mf)
            #pragma unroll
            for (int r = 0; r < 4; ++r) {
                int px = pw * 64 + mf * 16 + (lane >> 4) * 4 + r;
                float v = acc[mf][nf][r] + b;
                bVh[(rowbase + px) * 128 + o] = f2bf(v > 0.f ? v : 0.f);
            }
    }
}

// ---------------------------------------------------------------------------
// FUSED a1+amul: phase 1 computes a1 = relu(Wa1 @ [bVh;txc] + ba1) for this
// 128-px tile and stores it in LDS (two swizzled chunks, the exact layout
// stage64 would produce). Phase 2 runs amul's 5 M-tiles reading a1 fragments
// straight from LDS (no global a1h round-trip, no re-staging, one launch).
// Numerics bitwise-identical to the split kernels.
// ---------------------------------------------------------------------------
__global__ __launch_bounds__(256) void k_gemm_a1amul(const short* __restrict__ bVh,
        const short* __restrict__ txc, const short* __restrict__ wf1,
        const float* __restrict__ b1, const short* __restrict__ wf2,
        const float* __restrict__ b2, short* __restrict__ amulH) {
    __shared__ short lds[128 * 64];        // staging  (16 KB)
    __shared__ short a1l[2][128 * 64];     // a1 tile  (32 KB)
    GEMM_PROLOG
    // ---- phase 1: a1 (identical math to k_gemm_a1 with bx=0) ----
    {
        const short8b* wfv = (const short8b*)wf1;
        for (int cc = 0; cc < 10; ++cc) {
            __syncthreads();
            if (cc < 2) stage64(bVh, 128, cc * 64, rowbase, lds, tid);
            else        stage64(txc, 512, (cc - 2) * 64, rowbase, lds, tid);
            __syncthreads();
            GEMM_STEP(8)
        }
    }
    // write a1 into swizzled LDS (chunk = o>>6; elem = px*64 + ((o&63)^((px&7)<<3)))
    #pragma unroll
    for (int nf = 0; nf < 4; ++nf) {
        int oo = ow * 64 + nf * 16 + (lane & 15);   // 0..127 (bx=0 geometry)
        float b = b1[oo];
        #pragma unroll
        for (int mf = 0; mf < 4; ++mf)
            #pragma unroll
            for (int r = 0; r < 4; ++r) {
                int px = pw * 64 + mf * 16 + (lane >> 4) * 4 + r;
                float v = acc[mf][nf][r] + b;
                v = v > 0.f ? v : 0.f;
                int ch = oo & 63;
                a1l[oo >> 6][px * 64 + (ch ^ ((px & 7) << 3))] = f2bf(v);
            }
    }
    __syncthreads();
    // ---- phase 2: amul's 5 M-tiles; A-fragments from LDS-resident a1 ----
    const short8b* wfv2 = (const short8b*)wf2;
    for (int bx5 = 0; bx5 < 5; ++bx5) {
        f32x4 acc2[4][4] = {};
        #pragma unroll
        for (int cc = 0; cc < 2; ++cc) {
            short8b afr[4][2], bfr[4][2];
            #pragma unroll
            for (int mf = 0; mf < 4; ++mf)
                #pragma unroll
                for (int ks = 0; ks < 2; ++ks)
                    afr[mf][ks] = afrag(a1l[cc], pw, mf, ks, lane);
            #pragma unroll
            for (int nf = 0; nf < 4; ++nf) {
                int mt_g = bx5 * 8 + ow * 4 + nf;
                #pragma unroll
                for (int ks = 0; ks < 2; ++ks)
                    bfr[nf][ks] = wfv2[(((size_t)cc * 40 + mt_g) * 2 + ks) * 64 + lane];
            }
            #pragma unroll
            for (int ks = 0; ks < 2; ++ks)
                #pragma unroll
                for (int mf = 0; mf < 4; ++mf)
                    #pragma unroll
                    for (int nf = 0; nf < 4; ++nf)
                        acc2[mf][nf] = __builtin_amdgcn_mfma_f32_16x16x32_bf16(
                            afr[mf][ks], bfr[nf][ks], acc2[mf][nf], 0, 0, 0);
        }
        #pragma unroll
        for (int nf = 0; nf < 4; ++nf) {
            int o = bx5 * 128 + ow * 64 + nf * 16 + (lane & 15);
            float b = b2[o];
            #pragma unroll
            for (int mf = 0; mf < 4; ++mf)
                #pragma unroll
                for (int r = 0; r < 4; ++r) {
                    int px = pw * 64 + mf * 16 + (lane >> 4) * 4 + r;
                    float xv = acc2[mf][nf][r] + b;
                    float sg = 1.0f / (1.0f + expf(-xv));
                    float bval = (o < 128) ? bf2f(bVh[(rowbase + px) * 128 + o])
                                           : bf2f(txc[(rowbase + px) * 512 + o - 128]);
                    amulH[(rowbase + px) * 640 + o] = f2bf(sg * bval);
                }
        }
    }
}

// ---------------------------------------------------------------------------
// GAP finish + squeeze MLP + L2-normalize.
// ---------------------------------------------------------------------------
__global__ void k_wvec(const float* __restrict__ part, const float* __restrict__ Wt2,
                       const float* __restrict__ Wt3, float* __restrict__ wvec,
                       float* __restrict__ out_w) {
    int n = blockIdx.x, tid = threadIdx.x;
    __shared__ float sm1[256];
    __shared__ float sm2[64];
    __shared__ float smr[4];
    float s = 0.0f;
    #pragma unroll
    for (int t = 0; t < 32; ++t) s += part[(size_t)(n * 256 + tid) * 32 + t];
    sm1[tid] = s * (1.0f / 4096.0f);
    __syncthreads();
    if (tid < 64) {
        float a = 0.0f;
        for (int c = 0; c < 256; ++c) a = fmaf(Wt2[tid * 256 + c], sm1[c], a);
        sm2[tid] = a > 0.0f ? a : 0.0f;
    }
    __syncthreads();
    float w3 = 0.0f;
    for (int e = 0; e < 64; ++e) w3 = fmaf(Wt3[tid * 64 + e], sm2[e], w3);
    float q = w3 * w3;
    int lane = tid & 63, wv = tid >> 6;
    #pragma unroll
    for (int off = 32; off > 0; off >>= 1) q += __shfl_down(q, off);
    if (lane == 0) smr[wv] = q;
    __syncthreads();
    float nrm = sqrtf(smr[0] + smr[1] + smr[2] + smr[3]);
    nrm = fmaxf(nrm, 1e-12f);
    float w = w3 / nrm;
    wvec[n * 256 + tid] = w;
    out_w[n * 256 + tid] = w;
}

// ---------------------------------------------------------------------------
// MFMA implicit-GEMM conv3x3 — R10/R16-PROVEN configuration (130 us,
// 0 bank conflicts, VGPR 128, MfmaUtil ~31%). Unchanged.
// ---------------------------------------------------------------------------
#define WLOAD(dst, u, kss) { \
    _Pragma("unroll") for (int mf = 0; mf < 4; ++mf) { \
        int mt_g = bx * 8 + mw * 4 + mf; \
        dst[mf] = wf[(((size_t)(u) * 16 + mt_g) * 2 + (kss)) * 64 + lane]; } }

#define BLOAD(dst, kyv, kxv, ksv) { \
    _Pragma("unroll") for (int nf = 0; nf < 4; ++nf) { \
        int col = nf * 16 + (lane & 15); \
        int chc = col + (kxv); \
        int row_eff = nw + (kyv); \
        int elem = ((row_eff * 66 + chc) * 64 + (ksv) * 32 + (lane >> 4) * 8) \
                   ^ ((chc & 7) << 3); \
        dst[nf] = *(const short8b*)&lds_x[elem]; } }

#define MFMA16(W, B) { \
    _Pragma("unroll") for (int mf = 0; mf < 4; ++mf) \
        _Pragma("unroll") for (int nf = 0; nf < 4; ++nf) \
            acc[mf][nf] = __builtin_amdgcn_mfma_f32_16x16x32_bf16( \
                W[mf], B[nf], acc[mf][nf], 0, 0, 0); }

__global__ __launch_bounds__(512, 1) void k_conv3_mfma(
        const short* __restrict__ amulH, const short* __restrict__ Wfrag,
        const float* __restrict__ bot, float* __restrict__ out_a) {
    __shared__ short lds_x[6 * 66 * 64];   // 50688 B
    const int tid  = threadIdx.x;          // 0..511
    const int lane = tid & 63;
    const int wid  = tid >> 6;             // 0..7
    const int mw = wid & 1;
    const int nw = wid >> 1;
    const int qx = blockIdx.x;
    const int bx = blockIdx.y;
    const int n  = blockIdx.z;

    f32x4 acc[4][4] = {};
    const short8b* wf = (const short8b*)Wfrag;

    const int scol = tid >> 3, scg = tid & 7;
    short8b vreg[6];
    #pragma unroll
    for (int it = 0; it < 6; ++it) {
        int gr = qx * 4 - 1 + it;
        short8b t{};
        if (gr >= 0 && gr < 64)
            t = *(const short8b*)(amulH + ((size_t)(n * PP + gr * 64 + scol)) * 640 + scg * 8);
        vreg[it] = t;
    }
    if (tid < 96) {
        int rr = tid >> 4, side = (tid >> 3) & 1, cg = tid & 7;
        int chc = side ? 65 : 0;
        int elem = ((rr * 66 + chc) * 64 + cg * 8) ^ ((chc & 7) << 3);
        *(short8b*)&lds_x[elem] = short8b{};
    }

    short8b wA[4], wB[4], bfrA[4], bfrB[4];
    WLOAD(wA, 0, 0)

    for (int cc = 0; cc < 10; ++cc) {
        __syncthreads();
        {
            int chc = scol + 1;
            #pragma unroll
            for (int it = 0; it < 6; ++it) {
                int elem = ((it * 66 + chc) * 64 + scg * 8) ^ ((chc & 7) << 3);
                *(short8b*)&lds_x[elem] = vreg[it];
            }
        }
        __syncthreads();
        if (cc < 9) {
            #pragma unroll
            for (int it = 0; it < 6; ++it) {
                int gr = qx * 4 - 1 + it;
                short8b t{};
                if (gr >= 0 && gr < 64)
                    t = *(const short8b*)(amulH + ((size_t)(n * PP + gr * 64 + scol)) * 640
                                          + (cc + 1) * 64 + scg * 8);
                vreg[it] = t;
            }
        }
        BLOAD(bfrA, 0, 0, 0)
        #pragma unroll
        for (int h = 0; h < 18; ++h) {
            const bool even = ((h & 1) == 0);
            if (h < 17) {
                const int hn = h + 1;
                const int k9n = hn >> 1, ksn = hn & 1;
                const int kyn = k9n / 3, kxn = k9n % 3;
                const int un = k9n * 10 + cc;
                if (even) { BLOAD(bfrB, kyn, kxn, ksn) WLOAD(wB, un, ksn) }
                else      { BLOAD(bfrA, kyn, kxn, ksn) WLOAD(wA, un, ksn) }
            } else {
                WLOAD(wA, cc + 1, 0)   // dead buffer at h=17; next cc's h=0 weights
            }
            if (even) { MFMA16(wA, bfrA) } else { MFMA16(wB, bfrB) }
        }
    }
    #pragma unroll
    for (int mf = 0; mf < 4; ++mf) {
        int o = bx * 128 + mw * 64 + mf * 16 + (lane >> 4) * 4;
        #pragma unroll
        for (int r = 0; r < 4; ++r) {
            float bias = bot[o + r];
            #pragma unroll
            for (int nf = 0; nf < 4; ++nf) {
                int p = qx * 256 + nw * 64 + nf * 16 + (lane & 15);
                float v = acc[mf][nf][r] + bias;
                out_a[((size_t)(n * 256 + o + r)) * PP + p] = v > 0.f ? v : 0.f;
            }
        }
    }
}

// ---------------------------------------------------------------------------
extern "C" void kernel_launch(void* const* d_in, const int* in_sizes, int n_in,
                              void* d_out, int out_size, void* d_ws, size_t ws_size,
                              hipStream_t stream) {
    static const int want[18] = {
        8388608, 8388608, 8388608, 2097152, 196608, 256, 16384, 16384,
        65536, 256, 32768, 128, 81920, 128, 81920, 640, 1474560, 256
    };
    const void* ptr[18];
    bool used[64];
    for (int i = 0; i < 64; ++i) used[i] = false;
    bool ok = (n_in >= 18 && n_in <= 64);
    for (int k = 0; k < 18 && ok; ++k) {
        ptr[k] = nullptr;
        for (int i = 0; i < n_in; ++i) {
            if (!used[i] && in_sizes[i] == want[k]) { ptr[k] = d_in[i]; used[i] = true; break; }
        }
        if (!ptr[k]) ok = false;
    }
    if (!ok) { for (int k = 0; k < 18; ++k) ptr[k] = d_in[k]; }

    const float* sx1  = (const float*)ptr[0];
    const float* sx2  = (const float*)ptr[1];
    const float* t_hx = (const float*)ptr[2];
    const float* tx   = (const float*)ptr[3];
    const float* Wt1  = (const float*)ptr[4];
    const float* bt1  = (const float*)ptr[5];
    const float* Wt2  = (const float*)ptr[6];
    const float* Wt3  = (const float*)ptr[7];
    const float* WU   = (const float*)ptr[8];
    const float* bU   = (const float*)ptr[9];
    const float* WV   = (const float*)ptr[10];
    const float* bV   = (const float*)ptr[11];
    const float* Wa1  = (const float*)ptr[12];
    const float* ba1  = (const float*)ptr[13];
    const float* Wa2  = (const float*)ptr[14];
    const float* ba2  = (const float*)ptr[15];
    const float* Wot  = (const float*)ptr[16];
    const float* bot  = (const float*)ptr[17];

    // Workspace (same proven layout; a1h slot now unused):
    char* base = (char*)d_ws;
    short* txc   = (short*)base;
    short* bUh   = (short*)(base + (size_t)33554432);
    short* amulH = (short*)(base + (size_t)33554432);      // over dead bUh
    short* txh   = (short*)(base + (size_t)75497472);
    short* bVh   = (short*)(base + (size_t)75497472);      // over dead txh
    float* part  = (float*)(base + (size_t)92274688);
    float* wvec  = (float*)(base + (size_t)92536832);
    short* Wt1p  = (short*)(base + (size_t)92545024);
    short* WUp   = (short*)(base + (size_t)92938240);
    short* WVp   = (short*)(base + (size_t)93069312);
    short* Wa1p  = (short*)(base + (size_t)93134848);
    short* Wa2p  = (short*)(base + (size_t)93298688);
    short* Wotp  = (short*)(base + (size_t)93462528);

    float* out_a = (float*)d_out;
    float* out_w = out_a + (size_t)8 * 256 * PP;

    k_packall<<<dim3(944), 256, 0, stream>>>(Wt1, WU, WV, Wa1, Wa2, Wot,
                                             Wt1p, WUp, WVp, Wa1p, Wa2p, Wotp);
    k_t2h_all<<<dim3(64, 8, 8), 256, 0, stream>>>(t_hx, tx, txc, txh);
    k_up<<<dim3(512, 1, 8), 256, 0, stream>>>(txh, txc);

    // Tail GEMMs: pt-major grids (XCD co-residency, R20-validated)
    k_gemm_gap <<<dim3(32, 2, 8), 256, 0, stream>>>(sx1, txc, Wt1p, bt1, part);
    k_wvec     <<<dim3(8),        256, 0, stream>>>(part, Wt2, Wt3, wvec, out_w);
    k_gemm_bU  <<<dim3(32, 2, 8), 256, 0, stream>>>(sx2, WUp, bU, wvec, bUh);
    k_gemm_bV  <<<dim3(32, 1, 8), 256, 0, stream>>>(bUh, WVp, bV, bVh);
    k_gemm_a1amul<<<dim3(32, 1, 8), 256, 0, stream>>>(bVh, txc, Wa1p, ba1,
                                                      Wa2p, ba2, amulH);
    k_conv3_mfma<<<dim3(16, 2, 8), 512, 0, stream>>>(amulH, Wotp, bot, out_a);
}

// Round 22
// 267.253 us; speedup vs baseline: 1.1354x; 1.1354x over previous
//
#include <hip/hip_runtime.h>
#include <hip/hip_bf16.h>

#define PP 4096          // H*W
#define HH 64
#define WW 64

typedef __attribute__((ext_vector_type(8))) short short8b;   // 8 bf16
typedef __attribute__((ext_vector_type(4))) float f32x4;

static __device__ __forceinline__ float bf2f(short s) {
    union { unsigned int u; float f; } cv; cv.u = ((unsigned int)(unsigned short)s) << 16; return cv.f;
}
static __device__ __forceinline__ short f2bf(float f) {
    __hip_bfloat16 h = __float2bfloat16(f);
    return *reinterpret_cast<short*>(&h);
}

// ---------------------------------------------------------------------------
// Merged weight-prep (R15-validated): 5 1x1 packs + conv3 A-frag pack.
// ---------------------------------------------------------------------------
static __device__ __forceinline__ void pack16(const float* __restrict__ W,
                                              short* __restrict__ dst,
                                              int MT, int K, int s) {
    int total = MT * 2 * (K / 64) * 64;
    if (s >= total) return;
    int lane = s & 63;
    int rest = s >> 6;
    int ks = rest & 1; rest >>= 1;
    int mt = rest % MT;
    int cc = rest / MT;
    int o   = mt * 16 + (lane & 15);
    int ch0 = cc * 64 + ks * 32 + (lane >> 4) * 8;
    short8b v;
    #pragma unroll
    for (int j = 0; j < 8; ++j) v[j] = f2bf(W[(size_t)o * K + ch0 + j]);
    ((short8b*)dst)[s] = v;
}

__global__ void k_packall(const float* __restrict__ Wt1, const float* __restrict__ WU,
                          const float* __restrict__ WV, const float* __restrict__ Wa1,
                          const float* __restrict__ Wa2, const float* __restrict__ Wot,
                          short* __restrict__ Wt1p, short* __restrict__ WUp,
                          short* __restrict__ WVp, short* __restrict__ Wa1p,
                          short* __restrict__ Wa2p, short* __restrict__ Wotp) {
    int b = blockIdx.x, tid = threadIdx.x;
    if (b < 96)       { pack16(Wt1, Wt1p, 16, 768, (b)       * 256 + tid); }
    else if (b < 128) { pack16(WU,  WUp,  16, 256, (b - 96)  * 256 + tid); }
    else if (b < 144) { pack16(WV,  WVp,   8, 256, (b - 128) * 256 + tid); }
    else if (b < 184) { pack16(Wa1, Wa1p,  8, 640, (b - 144) * 256 + tid); }
    else if (b < 224) { pack16(Wa2, Wa2p, 40, 128, (b - 184) * 256 + tid); }
    else {
        int s = (b - 224) * 256 + tid;
        int lane = s & 63;
        int rest = s >> 6;
        int ks = rest & 1;  rest >>= 1;
        int mt = rest & 15; rest >>= 4;
        int cc = rest % 10;
        int k9 = rest / 10;
        int o   = mt * 16 + (lane & 15);
        int ch0 = cc * 64 + ks * 32 + (lane >> 4) * 8;
        short8b v{};
        #pragma unroll
        for (int j = 0; j < 8; ++j)
            v[j] = f2bf(Wot[((size_t)o * 640 + ch0 + j) * 9 + k9]);
        ((short8b*)Wotp)[s] = v;
    }
}

// ---------------------------------------------------------------------------
// Merged f32 NCHW -> bf16 NHWC transposes (t_hx, tx). Grid (64, 8, 8) x 256.
// ---------------------------------------------------------------------------
__global__ void k_t2h_all(const float* __restrict__ t_hx, const float* __restrict__ tx,
                          short* __restrict__ txc, short* __restrict__ txh) {
    __shared__ short T[64 * 65];
    int tid = threadIdx.x;
    int by = blockIdx.y;
    const float* src; short* dst; int P, pitch, yb;
    if (by < 4)  { src = t_hx; dst = txc; P = 4096; pitch = 512; yb = by; }
    else { if (blockIdx.x >= 16) return;
           src = tx;   dst = txh; P = 1024; pitch = 256; yb = by - 4; }
    int p0 = blockIdx.x * 64, c0 = yb * 64, n = blockIdx.z;
    #pragma unroll
    for (int it = 0; it < 16; ++it) {
        int slot = it * 256 + tid;
        int ch = slot >> 6, px = slot & 63;
        T[ch * 65 + px] = f2bf(src[((size_t)(n * 256 + c0 + ch)) * P + p0 + px]);
    }
    __syncthreads();
    #pragma unroll
    for (int it = 0; it < 16; ++it) {
        int slot = it * 256 + tid;
        int px = slot >> 6, ch = slot & 63;
        dst[((size_t)n * P + p0 + px) * pitch + c0 + ch] = T[ch * 65 + px];
    }
}

// ---------------------------------------------------------------------------
// Bilinear 2x upsample (align_corners) txh NHWC [n][1024][256] -> txc cols 256..511.
// ---------------------------------------------------------------------------
__global__ void k_up(const short* __restrict__ txh, short* __restrict__ txc) {
    int tid = threadIdx.x;
    int cg = tid & 31, pxl = tid >> 5;
    int px = blockIdx.x * 8 + pxl;
    int n  = blockIdx.z;
    int y = px >> 6, x = px & 63;
    const float s = 31.0f / 63.0f;
    float fy = y * s, fx = x * s;
    int y0 = (int)fy, x0 = (int)fx;
    int y1 = min(y0 + 1, 31), x1 = min(x0 + 1, 31);
    float wy = fy - (float)y0, wx = fx - (float)x0;
    const short8b* base = (const short8b*)(txh + ((size_t)n * 1024) * 256);
    short8b a = base[((size_t)(y0 * 32 + x0) * 256 + cg * 8) >> 3];
    short8b b = base[((size_t)(y0 * 32 + x1) * 256 + cg * 8) >> 3];
    short8b c = base[((size_t)(y1 * 32 + x0) * 256 + cg * 8) >> 3];
    short8b d = base[((size_t)(y1 * 32 + x1) * 256 + cg * 8) >> 3];
    short8b r;
    #pragma unroll
    for (int j = 0; j < 8; ++j) {
        float v = (bf2f(a[j]) * (1.f - wy) + bf2f(c[j]) * wy) * (1.f - wx)
                + (bf2f(b[j]) * (1.f - wy) + bf2f(d[j]) * wy) * wx;
        r[j] = f2bf(v);
    }
    *(short8b*)(txc + ((size_t)n * PP + px) * 512 + 256 + cg * 8) = r;
}

// ---------------------------------------------------------------------------
// GEMM LDS staging helpers (R15/R16-validated).
// ---------------------------------------------------------------------------
static __device__ __forceinline__ void stage64(const short* __restrict__ src, int pitch,
                                               int c0, size_t rowbase, short* lds, int tid) {
    #pragma unroll
    for (int it = 0; it < 4; ++it) {
        int idx = it * 256 + tid;
        int px = idx >> 3, cg = idx & 7;
        short8b v = *(const short8b*)(src + (rowbase + px) * (size_t)pitch + c0 + cg * 8);
        int elem = (px * 64 + cg * 8) ^ ((px & 7) << 3);
        *(short8b*)&lds[elem] = v;
    }
}
static __device__ __forceinline__ void stage64f(const float* __restrict__ ten, int C,
                                                int c0, int n, int pxbase,
                                                short* lds, int tid) {
    int chp = tid & 31;
    int pxg = tid >> 5;
    const float* p0 = ten + ((size_t)(n * C + c0 + chp * 2)) * PP + pxbase + pxg * 16;
    const float* p1 = p0 + PP;
    #pragma unroll
    for (int kq = 0; kq < 4; ++kq) {
        f32x4 a = *(const f32x4*)(p0 + kq * 4);
        f32x4 b = *(const f32x4*)(p1 + kq * 4);
        #pragma unroll
        for (int j = 0; j < 4; ++j) {
            int px = pxg * 16 + kq * 4 + j;
            int idx = px * 64 + ((chp * 2) ^ ((px & 7) << 3));
            unsigned int u = (unsigned int)(unsigned short)f2bf(a[j])
                           | ((unsigned int)(unsigned short)f2bf(b[j]) << 16);
            *(unsigned int*)&lds[idx] = u;
        }
    }
}
static __device__ __forceinline__ short8b afrag(const short* lds, int pw, int mf, int ks, int lane) {
    int px = pw * 64 + mf * 16 + (lane & 15);
    int elem = (px * 64 + ks * 32 + ((lane >> 4) * 8)) ^ ((px & 7) << 3);
    return *(const short8b*)&lds[elem];
}
// XCD co-residency (R20-validated): pt on blockIdx.x, bx on blockIdx.y.
#define GEMM_PROLOG \
    int tid = threadIdx.x, lane = tid & 63, wid = tid >> 6; \
    int pw = wid & 1, ow = wid >> 1; \
    int bx = blockIdx.y, pt = blockIdx.x, n = blockIdx.z; \
    size_t rowbase = (size_t)n * PP + pt * 128; \
    f32x4 acc[4][4] = {}; (void)bx; (void)rowbase;
#define GEMM_STEP(MT) { \
    short8b afr[4][2], bfr[4][2]; \
    _Pragma("unroll") for (int mf = 0; mf < 4; ++mf) \
        _Pragma("unroll") for (int ks = 0; ks < 2; ++ks) afr[mf][ks] = afrag(lds, pw, mf, ks, lane); \
    _Pragma("unroll") for (int nf = 0; nf < 4; ++nf) { \
        int mt_g = bx * 8 + ow * 4 + nf; \
        _Pragma("unroll") for (int ks = 0; ks < 2; ++ks) \
            bfr[nf][ks] = wfv[(((size_t)cc * (MT) + mt_g) * 2 + ks) * 64 + lane]; } \
    _Pragma("unroll") for (int ks = 0; ks < 2; ++ks) \
        _Pragma("unroll") for (int mf = 0; mf < 4; ++mf) \
            _Pragma("unroll") for (int nf = 0; nf < 4; ++nf) \
                acc[mf][nf] = __builtin_amdgcn_mfma_f32_16x16x32_bf16(afr[mf][ks], bfr[nf][ks], acc[mf][nf], 0, 0, 0); }

// ---------------------------------------------------------------------------
// GAP GEMM: K=768 ([sx1 f32-direct; txc]); relu+px-sum -> part.
// ---------------------------------------------------------------------------
__global__ __launch_bounds__(256) void k_gemm_gap(const float* __restrict__ sx1,
        const short* __restrict__ txc, const short* __restrict__ wf,
        const float* __restrict__ bias, float* __restrict__ part) {
    __shared__ short lds[128 * 64];
    __shared__ float red[128 * 2];
    GEMM_PROLOG
    const short8b* wfv = (const short8b*)wf;
    for (int cc = 0; cc < 12; ++cc) {
        __syncthreads();
        if (cc < 4) stage64f(sx1, 256, cc * 64, n, pt * 128, lds, tid);
        else        stage64(txc, 512, (cc - 4) * 64, rowbase, lds, tid);
        __syncthreads();
        GEMM_STEP(16)
    }
    #pragma unroll
    for (int nf = 0; nf < 4; ++nf) {
        int o = bx * 128 + ow * 64 + nf * 16 + (lane & 15);
        float b = bias[o];
        float s = 0.f;
        #pragma unroll
        for (int mf = 0; mf < 4; ++mf)
            #pragma unroll
            for (int r = 0; r < 4; ++r) {
                float v = acc[mf][nf][r] + b;
                s += v > 0.f ? v : 0.f;
            }
        s += __shfl_xor(s, 16);
        s += __shfl_xor(s, 32);
        if (lane < 16) red[(ow * 64 + nf * 16 + lane) * 2 + pw] = s;
    }
    __syncthreads();
    if (tid < 128)
        part[((size_t)n * 256 + bx * 128 + tid) * 32 + pt] = red[tid * 2] + red[tid * 2 + 1];
}

// ---------------------------------------------------------------------------
// bU GEMM: K=256 (sx2 f32-direct); relu(+bias)*wvec -> bUh NHWC.
// ---------------------------------------------------------------------------
__global__ __launch_bounds__(256) void k_gemm_bU(const float* __restrict__ sx2,
        const short* __restrict__ wf, const float* __restrict__ bias,
        const float* __restrict__ wvec, short* __restrict__ bUh) {
    __shared__ short lds[128 * 64];
    GEMM_PROLOG
    const short8b* wfv = (const short8b*)wf;
    for (int cc = 0; cc < 4; ++cc) {
        __syncthreads();
        stage64f(sx2, 256, cc * 64, n, pt * 128, lds, tid);
        __syncthreads();
        GEMM_STEP(16)
    }
    #pragma unroll
    for (int nf = 0; nf < 4; ++nf) {
        int o = bx * 128 + ow * 64 + nf * 16 + (lane & 15);
        float b = bias[o], wv = wvec[n * 256 + o];
        #pragma unroll
        for (int mf = 0; mf < 4; ++mf)
            #pragma unroll
            for (int r = 0; r < 4; ++r) {
                int px = pw * 64 + mf * 16 + (lane >> 4) * 4 + r;
                float v = acc[mf][nf][r] + b;
                v = v > 0.f ? v : 0.f;
                bUh[(rowbase + px) * 256 + o] = f2bf(v * wv);
            }
    }
}

// ---------------------------------------------------------------------------
// bV GEMM: M=128, K=256 (bUh); relu -> bVh [n][px][128].
// ---------------------------------------------------------------------------
__global__ __launch_bounds__(256) void k_gemm_bV(const short* __restrict__ bUh,
        const short* __restrict__ wf, const float* __restrict__ bias,
        short* __restrict__ bVh) {
    __shared__ short lds[128 * 64];
    GEMM_PROLOG
    const short8b* wfv = (const short8b*)wf;
    for (int cc = 0; cc < 4; ++cc) {
        __syncthreads();
        stage64(bUh, 256, cc * 64, rowbase, lds, tid);
        __syncthreads();
        GEMM_STEP(8)
    }
    #pragma unroll
    for (int nf = 0; nf < 4; ++nf) {
        int o = ow * 64 + nf * 16 + (lane & 15);
        float b = bias[o];
        #pragma unroll
        for (int mf = 0; mf < 4; ++mf)
            #pragma unroll
            for (int r = 0; r < 4; ++r) {
                int px = pw * 64 + mf * 16 + (lane >> 4) * 4 + r;
                float v = acc[mf][nf][r] + b;
                bVh[(rowbase + px) * 128 + o] = f2bf(v > 0.f ? v : 0.f);
            }
    }
}

// ---------------------------------------------------------------------------
// a1 GEMM: M=128, K=640 ([bVh;txc]); relu -> a1h [n][px][128].
// ---------------------------------------------------------------------------
__global__ __launch_bounds__(256) void k_gemm_a1(const short* __restrict__ bVh,
        const short* __restrict__ txc, const short* __restrict__ wf,
        const float* __restrict__ bias, short* __restrict__ a1h) {
    __shared__ short lds[128 * 64];
    GEMM_PROLOG
    const short8b* wfv = (const short8b*)wf;
    for (int cc = 0; cc < 10; ++cc) {
        __syncthreads();
        if (cc < 2) stage64(bVh, 128, cc * 64, rowbase, lds, tid);
        else        stage64(txc, 512, (cc - 2) * 64, rowbase, lds, tid);
        __syncthreads();
        GEMM_STEP(8)
    }
    #pragma unroll
    for (int nf = 0; nf < 4; ++nf) {
        int o = ow * 64 + nf * 16 + (lane & 15);
        float b = bias[o];
        #pragma unroll
        for (int mf = 0; mf < 4; ++mf)
            #pragma unroll
            for (int r = 0; r < 4; ++r) {
                int px = pw * 64 + mf * 16 + (lane >> 4) * 4 + r;
                float v = acc[mf][nf][r] + b;
                a1h[(rowbase + px) * 128 + o] = f2bf(v > 0.f ? v : 0.f);
            }
    }
}

// ---------------------------------------------------------------------------
// amul GEMM: M=640, K=128 (a1h); sigmoid * [bVh;txc] -> amulH NHWC.
// ---------------------------------------------------------------------------
__global__ __launch_bounds__(256) void k_gemm_amul(const short* __restrict__ a1h,
        const short* __restrict__ wf, const float* __restrict__ bias,
        const short* __restrict__ bVh, const short* __restrict__ txc,
        short* __restrict__ amulH) {
    __shared__ short lds[128 * 64];
    GEMM_PROLOG
    const short8b* wfv = (const short8b*)wf;
    for (int cc = 0; cc < 2; ++cc) {
        __syncthreads();
        stage64(a1h, 128, cc * 64, rowbase, lds, tid);
        __syncthreads();
        GEMM_STEP(40)
    }
    #pragma unroll
    for (int nf = 0; nf < 4; ++nf) {
        int o = bx * 128 + ow * 64 + nf * 16 + (lane & 15);
        float b = bias[o];
        #pragma unroll
        for (int mf = 0; mf < 4; ++mf)
            #pragma unroll
            for (int r = 0; r < 4; ++r) {
                int px = pw * 64 + mf * 16 + (lane >> 4) * 4 + r;
                float xv = acc[mf][nf][r] + b;
                float sg = 1.0f / (1.0f + expf(-xv));
                float bval = (o < 128) ? bf2f(bVh[(rowbase + px) * 128 + o])
                                       : bf2f(txc[(rowbase + px) * 512 + o - 128]);
                amulH[(rowbase + px) * 640 + o] = f2bf(sg * bval);
            }
    }
}

// ---------------------------------------------------------------------------
// GAP finish + squeeze MLP + L2-normalize.
// ---------------------------------------------------------------------------
__global__ void k_wvec(const float* __restrict__ part, const float* __restrict__ Wt2,
                       const float* __restrict__ Wt3, float* __restrict__ wvec,
                       float* __restrict__ out_w) {
    int n = blockIdx.x, tid = threadIdx.x;
    __shared__ float sm1[256];
    __shared__ float sm2[64];
    __shared__ float smr[4];
    float s = 0.0f;
    #pragma unroll
    for (int t = 0; t < 32; ++t) s += part[(size_t)(n * 256 + tid) * 32 + t];
    sm1[tid] = s * (1.0f / 4096.0f);
    __syncthreads();
    if (tid < 64) {
        float a = 0.0f;
        for (int c = 0; c < 256; ++c) a = fmaf(Wt2[tid * 256 + c], sm1[c], a);
        sm2[tid] = a > 0.0f ? a : 0.0f;
    }
    __syncthreads();
    float w3 = 0.0f;
    for (int e = 0; e < 64; ++e) w3 = fmaf(Wt3[tid * 64 + e], sm2[e], w3);
    float q = w3 * w3;
    int lane = tid & 63, wv = tid >> 6;
    #pragma unroll
    for (int off = 32; off > 0; off >>= 1) q += __shfl_down(q, off);
    if (lane == 0) smr[wv] = q;
    __syncthreads();
    float nrm = sqrtf(smr[0] + smr[1] + smr[2] + smr[3]);
    nrm = fmaxf(nrm, 1e-12f);
    float w = w3 / nrm;
    wvec[n * 256 + tid] = w;
    out_w[n * 256 + tid] = w;
}

// ---------------------------------------------------------------------------
// MFMA implicit-GEMM conv3x3 — R10/R16-PROVEN configuration (130 us,
// 0 bank conflicts, VGPR 128, MfmaUtil ~31%). Unchanged.
// ---------------------------------------------------------------------------
#define WLOAD(dst, u, kss) { \
    _Pragma("unroll") for (int mf = 0; mf < 4; ++mf) { \
        int mt_g = bx * 8 + mw * 4 + mf; \
        dst[mf] = wf[(((size_t)(u) * 16 + mt_g) * 2 + (kss)) * 64 + lane]; } }

#define BLOAD(dst, kyv, kxv, ksv) { \
    _Pragma("unroll") for (int nf = 0; nf < 4; ++nf) { \
        int col = nf * 16 + (lane & 15); \
        int chc = col + (kxv); \
        int row_eff = nw + (kyv); \
        int elem = ((row_eff * 66 + chc) * 64 + (ksv) * 32 + (lane >> 4) * 8) \
                   ^ ((chc & 7) << 3); \
        dst[nf] = *(const short8b*)&lds_x[elem]; } }

#define MFMA16(W, B) { \
    _Pragma("unroll") for (int mf = 0; mf < 4; ++mf) \
        _Pragma("unroll") for (int nf = 0; nf < 4; ++nf) \
            acc[mf][nf] = __builtin_amdgcn_mfma_f32_16x16x32_bf16( \
                W[mf], B[nf], acc[mf][nf], 0, 0, 0); }

__global__ __launch_bounds__(512, 1) void k_conv3_mfma(
        const short* __restrict__ amulH, const short* __restrict__ Wfrag,
        const float* __restrict__ bot, float* __restrict__ out_a) {
    __shared__ short lds_x[6 * 66 * 64];   // 50688 B
    const int tid  = threadIdx.x;          // 0..511
    const int lane = tid & 63;
    const int wid  = tid >> 6;             // 0..7
    const int mw = wid & 1;
    const int nw = wid >> 1;
    const int qx = blockIdx.x;
    const int bx = blockIdx.y;
    const int n  = blockIdx.z;

    f32x4 acc[4][4] = {};
    const short8b* wf = (const short8b*)Wfrag;

    const int scol = tid >> 3, scg = tid & 7;
    short8b vreg[6];
    #pragma unroll
    for (int it = 0; it < 6; ++it) {
        int gr = qx * 4 - 1 + it;
        short8b t{};
        if (gr >= 0 && gr < 64)
            t = *(const short8b*)(amulH + ((size_t)(n * PP + gr * 64 + scol)) * 640 + scg * 8);
        vreg[it] = t;
    }
    if (tid < 96) {
        int rr = tid >> 4, side = (tid >> 3) & 1, cg = tid & 7;
        int chc = side ? 65 : 0;
        int elem = ((rr * 66 + chc) * 64 + cg * 8) ^ ((chc & 7) << 3);
        *(short8b*)&lds_x[elem] = short8b{};
    }

    short8b wA[4], wB[4], bfrA[4], bfrB[4];
    WLOAD(wA, 0, 0)

    for (int cc = 0; cc < 10; ++cc) {
        __syncthreads();
        {
            int chc = scol + 1;
            #pragma unroll
            for (int it = 0; it < 6; ++it) {
                int elem = ((it * 66 + chc) * 64 + scg * 8) ^ ((chc & 7) << 3);
                *(short8b*)&lds_x[elem] = vreg[it];
            }
        }
        __syncthreads();
        if (cc < 9) {
            #pragma unroll
            for (int it = 0; it < 6; ++it) {
                int gr = qx * 4 - 1 + it;
                short8b t{};
                if (gr >= 0 && gr < 64)
                    t = *(const short8b*)(amulH + ((size_t)(n * PP + gr * 64 + scol)) * 640
                                          + (cc + 1) * 64 + scg * 8);
                vreg[it] = t;
            }
        }
        BLOAD(bfrA, 0, 0, 0)
        #pragma unroll
        for (int h = 0; h < 18; ++h) {
            const bool even = ((h & 1) == 0);
            if (h < 17) {
                const int hn = h + 1;
                const int k9n = hn >> 1, ksn = hn & 1;
                const int kyn = k9n / 3, kxn = k9n % 3;
                const int un = k9n * 10 + cc;
                if (even) { BLOAD(bfrB, kyn, kxn, ksn) WLOAD(wB, un, ksn) }
                else      { BLOAD(bfrA, kyn, kxn, ksn) WLOAD(wA, un, ksn) }
            } else {
                WLOAD(wA, cc + 1, 0)   // dead buffer at h=17; next cc's h=0 weights
            }
            if (even) { MFMA16(wA, bfrA) } else { MFMA16(wB, bfrB) }
        }
    }
    #pragma unroll
    for (int mf = 0; mf < 4; ++mf) {
        int o = bx * 128 + mw * 64 + mf * 16 + (lane >> 4) * 4;
        #pragma unroll
        for (int r = 0; r < 4; ++r) {
            float bias = bot[o + r];
            #pragma unroll
            for (int nf = 0; nf < 4; ++nf) {
                int p = qx * 256 + nw * 64 + nf * 16 + (lane & 15);
                float v = acc[mf][nf][r] + bias;
                out_a[((size_t)(n * 256 + o + r)) * PP + p] = v > 0.f ? v : 0.f;
            }
        }
    }
}

// ---------------------------------------------------------------------------
extern "C" void kernel_launch(void* const* d_in, const int* in_sizes, int n_in,
                              void* d_out, int out_size, void* d_ws, size_t ws_size,
                              hipStream_t stream) {
    static const int want[18] = {
        8388608, 8388608, 8388608, 2097152, 196608, 256, 16384, 16384,
        65536, 256, 32768, 128, 81920, 128, 81920, 640, 1474560, 256
    };
    const void* ptr[18];
    bool used[64];
    for (int i = 0; i < 64; ++i) used[i] = false;
    bool ok = (n_in >= 18 && n_in <= 64);
    for (int k = 0; k < 18 && ok; ++k) {
        ptr[k] = nullptr;
        for (int i = 0; i < n_in; ++i) {
            if (!used[i] && in_sizes[i] == want[k]) { ptr[k] = d_in[i]; used[i] = true; break; }
        }
        if (!ptr[k]) ok = false;
    }
    if (!ok) { for (int k = 0; k < 18; ++k) ptr[k] = d_in[k]; }

    const float* sx1  = (const float*)ptr[0];
    const float* sx2  = (const float*)ptr[1];
    const float* t_hx = (const float*)ptr[2];
    const float* tx   = (const float*)ptr[3];
    const float* Wt1  = (const float*)ptr[4];
    const float* bt1  = (const float*)ptr[5];
    const float* Wt2  = (const float*)ptr[6];
    const float* Wt3  = (const float*)ptr[7];
    const float* WU   = (const float*)ptr[8];
    const float* bU   = (const float*)ptr[9];
    const float* WV   = (const float*)ptr[10];
    const float* bV   = (const float*)ptr[11];
    const float* Wa1  = (const float*)ptr[12];
    const float* ba1  = (const float*)ptr[13];
    const float* Wa2  = (const float*)ptr[14];
    const float* ba2  = (const float*)ptr[15];
    const float* Wot  = (const float*)ptr[16];
    const float* bot  = (const float*)ptr[17];

    // Workspace (R20-proven layout):
    char* base = (char*)d_ws;
    short* txc   = (short*)base;
    short* bUh   = (short*)(base + (size_t)33554432);
    short* amulH = (short*)(base + (size_t)33554432);      // over dead bUh
    short* txh   = (short*)(base + (size_t)75497472);
    short* bVh   = (short*)(base + (size_t)75497472);      // over dead txh
    short* a1h   = (short*)(base + (size_t)83886080);
    float* part  = (float*)(base + (size_t)92274688);
    float* wvec  = (float*)(base + (size_t)92536832);
    short* Wt1p  = (short*)(base + (size_t)92545024);
    short* WUp   = (short*)(base + (size_t)92938240);
    short* WVp   = (short*)(base + (size_t)93069312);
    short* Wa1p  = (short*)(base + (size_t)93134848);
    short* Wa2p  = (short*)(base + (size_t)93298688);
    short* Wotp  = (short*)(base + (size_t)93462528);

    float* out_a = (float*)d_out;
    float* out_w = out_a + (size_t)8 * 256 * PP;

    k_packall<<<dim3(944), 256, 0, stream>>>(Wt1, WU, WV, Wa1, Wa2, Wot,
                                             Wt1p, WUp, WVp, Wa1p, Wa2p, Wotp);
    k_t2h_all<<<dim3(64, 8, 8), 256, 0, stream>>>(t_hx, tx, txc, txh);
    k_up<<<dim3(512, 1, 8), 256, 0, stream>>>(txh, txc);

    // Tail GEMMs: pt-major grids (XCD co-residency, R20-validated)
    k_gemm_gap <<<dim3(32, 2, 8), 256, 0, stream>>>(sx1, txc, Wt1p, bt1, part);
    k_wvec     <<<dim3(8),        256, 0, stream>>>(part, Wt2, Wt3, wvec, out_w);
    k_gemm_bU  <<<dim3(32, 2, 8), 256, 0, stream>>>(sx2, WUp, bU, wvec, bUh);
    k_gemm_bV  <<<dim3(32, 1, 8), 256, 0, stream>>>(bUh, WVp, bV, bVh);
    k_gemm_a1  <<<dim3(32, 1, 8), 256, 0, stream>>>(bVh, txc, Wa1p, ba1, a1h);
    k_gemm_amul<<<dim3(32, 5, 8), 256, 0, stream>>>(a1h, Wa2p, ba2, bVh, txc, amulH);
    k_conv3_mfma<<<dim3(16, 2, 8), 512, 0, stream>>>(amulH, Wotp, bot, out_a);
}